// Round 8
// baseline (390.798 us; speedup 1.0000x reference)
//
#include <hip/hip_runtime.h>

#define D 64
#define BK_SHIFT 6              // 64 nodes per bucket
#define BK_CAP 8192             // staged entries per bucket (mean ~1600)
#define NBLK 256                // radix pass blocks

__device__ __forceinline__ float bfbits2f(unsigned short b) {
    union { unsigned int u; float f; } c;
    c.u = ((unsigned int)b) << 16;
    return c.f;
}

__device__ __forceinline__ unsigned short f2bfbits(float f) {
    union { float f; unsigned int u; } c;
    c.f = f;
    unsigned int u = c.u;
    unsigned int lsb = (u >> 16) & 1u;
    u += 0x7fffu + lsb;           // round-to-nearest-even
    return (unsigned short)(u >> 16);
}

__device__ __forceinline__ float ldmix(const void* p, size_t i, int isf32) {
    return isf32 ? ((const float*)p)[i] : bfbits2f(((const unsigned short*)p)[i]);
}

// ---- dtype sniff -----------------------------------------------------------
__global__ void sniff_kernel(const unsigned short* __restrict__ W, int* __restrict__ flag) {
    int t = threadIdx.x;
    bool bad = false;
    for (int i = t; i < 256; i += 64) {
        float v = bfbits2f(W[i]);
        if (!(v == v) || fabsf(v) > 1e4f) bad = true;
    }
    unsigned long long m = __ballot(bad);
    if (t == 0) *flag = (m != 0ull) ? 1 : 0;
}

// ---- param conversion ------------------------------------------------------
#define OW1 0
#define OW2 4096
#define OW3 8192
#define OB1 12288
#define OB2 12352
#define OB3 12416
#define OG  12480
#define OBE 12544
#define OPA 12608

__global__ void cvt_params_kernel(const void* W1, const void* b1, const void* W2, const void* b2,
                                  const void* W3, const void* b3, const void* pa, const void* g,
                                  const void* be, const int* __restrict__ flag,
                                  float* __restrict__ P) {
    int isf = *flag;
    int t = threadIdx.x;                 // one block of 256
    for (int i = t; i < D * D; i += 256) {
        P[OW1 + i] = ldmix(W1, i, isf);
        P[OW2 + i] = ldmix(W2, i, isf);
        P[OW3 + i] = ldmix(W3, i, isf);
    }
    if (t < D) {
        P[OB1 + t] = ldmix(b1, t, isf);
        P[OB2 + t] = ldmix(b2, t, isf);
        P[OB3 + t] = ldmix(b3, t, isf);
        P[OG  + t] = ldmix(g,  t, isf);
        P[OBE + t] = ldmix(be, t, isf);
    }
    if (t == 0) P[OPA] = ldmix(pa, 0, isf);
}

// ---- deterministic two-pass radix binning (no global atomics) --------------
// H layout: H[bucket * NBLK + block]

__global__ void binA1_kernel(const int* __restrict__ dst, int E, int NB, int CH,
                             int* __restrict__ H) {
    __shared__ int h[1024];
    int t = threadIdx.x, bb = blockIdx.x;
    for (int i = t; i < NB; i += 256) h[i] = 0;
    __syncthreads();
    int beg = bb * CH, end = beg + CH; if (end > E) end = E;
    for (int e = beg + t; e < end; e += 256)
        atomicAdd(&h[dst[e] >> BK_SHIFT], 1);
    __syncthreads();
    for (int i = t; i < NB; i += 256) H[i * NBLK + bb] = h[i];
}

// per-bucket exclusive scan of the NBLK block-counts; T[b] = bucket total
__global__ void binA2_kernel(int* __restrict__ H, int* __restrict__ T) {
    __shared__ int ws[4];
    __shared__ int wx[4];
    int b = blockIdx.x, t = threadIdx.x;
    int lane = t & 63, wid = t >> 6;
    int v = H[b * NBLK + t];
    int incl = v;
#pragma unroll
    for (int off = 1; off < 64; off <<= 1) {
        int u = __shfl_up(incl, off, 64);
        if (lane >= off) incl += u;
    }
    if (lane == 63) ws[wid] = incl;
    __syncthreads();
    if (t == 0) {
        int s = 0;
#pragma unroll
        for (int j = 0; j < 4; ++j) { wx[j] = s; s += ws[j]; }
        T[b] = s;
    }
    __syncthreads();
    H[b * NBLK + t] = wx[wid] + incl - v;
}

// single-block scan of bucket totals -> bucket_beg
__global__ void binA3_kernel(const int* __restrict__ T, int* __restrict__ bucket_beg, int NB) {
    __shared__ int tile[1024];
    int t = threadIdx.x;
    int v = (t < NB) ? T[t] : 0;
    tile[t] = v;
    __syncthreads();
    for (int off = 1; off < 1024; off <<= 1) {
        int add = (t >= off) ? tile[t - off] : 0;
        __syncthreads();
        tile[t] += add;
        __syncthreads();
    }
    if (t < NB) bucket_beg[t] = tile[t] - v;
    if (t == NB - 1) bucket_beg[NB] = tile[t];
}

// scatter edges into bucket-grouped tmp via LDS cursors (deterministic ranges)
__global__ void binA4_kernel(const int* __restrict__ src, const int* __restrict__ dst,
                             const int* __restrict__ H, const int* __restrict__ bucket_beg,
                             unsigned int* __restrict__ tmp, int E, int NB, int CH) {
    __shared__ int O[1024];
    int t = threadIdx.x, bb = blockIdx.x;
    for (int i = t; i < NB; i += 256) O[i] = bucket_beg[i] + H[i * NBLK + bb];
    __syncthreads();
    int beg = bb * CH, end = beg + CH; if (end > E) end = E;
    for (int e = beg + t; e < end; e += 256) {
        int d = dst[e];
        int p = atomicAdd(&O[d >> BK_SHIFT], 1);
        tmp[p] = ((unsigned int)src[e] << BK_SHIFT) | (unsigned int)(d & 63);
    }
}

// one block per bucket: per-node count + scan + L2-local scatter
__global__ void binB_kernel(const unsigned int* __restrict__ tmp, const int* __restrict__ bucket_beg,
                            int* __restrict__ row_beg, int* __restrict__ cnt,
                            float* __restrict__ dinv, int* __restrict__ col, int N) {
    __shared__ unsigned int ent[BK_CAP];
    __shared__ int lcnt[64], lcur[64];
    int b = blockIdx.x, t = threadIdx.x;
    int beg = bucket_beg[b], end = bucket_beg[b + 1];
    int m = end - beg;
    bool staged = (m <= BK_CAP);
    if (t < 64) lcnt[t] = 0;
    __syncthreads();
    for (int i = t; i < m; i += 256) {
        unsigned int e = tmp[beg + i];
        if (staged) ent[i] = e;
        atomicAdd(&lcnt[e & 63u], 1);
    }
    __syncthreads();
    if (t < 64) {
        int v = lcnt[t];
        int incl = v;
#pragma unroll
        for (int off = 1; off < 64; off <<= 1) {
            int u = __shfl_up(incl, off, 64);
            if (t >= off) incl += u;
        }
        int excl = incl - v;
        lcur[t] = excl;
        int node = b * 64 + t;
        if (node < N) {
            row_beg[node] = beg + excl;
            cnt[node]     = v;
            dinv[node]    = rsqrtf((float)(v + 1));
        }
    }
    __syncthreads();
    for (int i = t; i < m; i += 256) {
        unsigned int e = staged ? ent[i] : tmp[beg + i];
        int p = atomicAdd(&lcur[e & 63u], 1);
        col[beg + p] = (int)(e >> BK_SHIFT);
    }
}

// ---- feature kernels -------------------------------------------------------

__global__ void prescale_kernel(const void* __restrict__ X, const float* __restrict__ dinv,
                                const int* __restrict__ flag, unsigned short* __restrict__ Xs, int n) {
    int isf = *flag;
    int gid  = blockIdx.x * blockDim.x + threadIdx.x;
    int node = gid >> 6;
    if (node >= n) return;
    Xs[gid] = f2bfbits(dinv[node] * ldmix(X, (size_t)gid, isf));
}

__device__ __forceinline__ void acc8(float* a, uint4 v) {
    a[0] += bfbits2f((unsigned short)(v.x & 0xffffu));
    a[1] += bfbits2f((unsigned short)(v.x >> 16));
    a[2] += bfbits2f((unsigned short)(v.y & 0xffffu));
    a[3] += bfbits2f((unsigned short)(v.y >> 16));
    a[4] += bfbits2f((unsigned short)(v.z & 0xffffu));
    a[5] += bfbits2f((unsigned short)(v.z >> 16));
    a[6] += bfbits2f((unsigned short)(v.w & 0xffffu));
    a[7] += bfbits2f((unsigned short)(v.w >> 16));
}

// vectorized gather with batched loads: wave covers 8 source rows per load inst
// (slot=lane>>3 picks row, sub=lane&7 picks 16B chunk). Up to 8 loads issued
// back-to-back into v[8] before any accumulate -> 8 loads in flight per wave.
__device__ __forceinline__ void aggregate8(const unsigned short* __restrict__ Xs,
                                           const int* __restrict__ row_beg,
                                           const int* __restrict__ cnt,
                                           const int* __restrict__ col,
                                           const float* __restrict__ dinv,
                                           int node, int lane, float* __restrict__ x8) {
    const int slot = lane >> 3;
    const int sub  = lane & 7;
    // self-loop row: issue early, consume at the end
    uint4 sv = *((const uint4*)(Xs + ((size_t)node << 6)) + sub);
    float a[8];
#pragma unroll
    for (int j = 0; j < 8; ++j) a[j] = 0.f;
    int beg = row_beg[node], m_tot = cnt[node];
    for (int chunk = 0; chunk < m_tot; chunk += 64) {
        int m = m_tot - chunk; if (m > 64) m = 64;
        int idx = (lane < m) ? col[beg + chunk + lane] : 0;
        int ni = (m + 7) >> 3;                       // 1..8 row-batches
        uint4 v[8];
#pragma unroll
        for (int i = 0; i < 8; ++i) {                // issue phase (no waits between)
            if (i < ni) {
                int s = __shfl(idx, i * 8 + slot, 64);   // r>=m -> idx lane holds 0 (safe)
                v[i] = *((const uint4*)(Xs + ((size_t)s << 6)) + sub);
            }
        }
#pragma unroll
        for (int i = 0; i < 8; ++i) {                // consume phase
            if (i < ni) {
                if (i * 8 + slot < m) acc8(a, v[i]);
            }
        }
    }
    // reduce the 8 row-slots (flip lane bits 3..5; sub preserved)
#pragma unroll
    for (int off = 8; off < 64; off <<= 1) {
#pragma unroll
        for (int j = 0; j < 8; ++j) a[j] += __shfl_xor(a[j], off, 64);
    }
    acc8(a, sv);                                     // self loop
    float dn = dinv[node];
#pragma unroll
    for (int j = 0; j < 8; ++j) x8[j] = dn * a[j];
}

// wave GEMM with 4-way accumulator ILP; feature k lives in lane k>>3, elem k&7
__device__ __forceinline__ float wave_gemm(const float* __restrict__ Wl, const float* x8, int lane) {
    float acc0 = 0.f, acc1 = 0.f, acc2 = 0.f, acc3 = 0.f;
#pragma unroll
    for (int k = 0; k < D; k += 4) {
        acc0 = fmaf(__shfl(x8[(k    ) & 7], (k    ) >> 3, 64), Wl[(k    ) * D + lane], acc0);
        acc1 = fmaf(__shfl(x8[(k + 1) & 7], (k + 1) >> 3, 64), Wl[(k + 1) * D + lane], acc1);
        acc2 = fmaf(__shfl(x8[(k + 2) & 7], (k + 2) >> 3, 64), Wl[(k + 2) * D + lane], acc2);
        acc3 = fmaf(__shfl(x8[(k + 3) & 7], (k + 3) >> 3, 64), Wl[(k + 3) * D + lane], acc3);
    }
    return (acc0 + acc1) + (acc2 + acc3);
}

__global__ void __launch_bounds__(256)
agg_gemm_kernel(const unsigned short* __restrict__ Xs,
                const int* __restrict__ row_beg, const int* __restrict__ cnt,
                const int* __restrict__ col, const float* __restrict__ dinv,
                const float* __restrict__ W, const float* __restrict__ b,
                const float* __restrict__ pa,
                unsigned short* __restrict__ Xout, int n) {
    __shared__ float Wl[D * D];
    int t = threadIdx.x;
    for (int i = t; i < D * D; i += 256) Wl[i] = W[i];
    __syncthreads();
    int wid = t >> 6, lane = t & 63;
    int node = blockIdx.x * 4 + wid;
    if (node >= n) return;
    float bl = b[lane];                               // hoisted scalar-path loads
    float a  = pa[0];
    float x8[8];
    aggregate8(Xs, row_beg, cnt, col, dinv, node, lane, x8);
    float acc = wave_gemm(Wl, x8, lane) + bl;
    acc = (acc >= 0.f) ? acc : a * acc;
    acc *= dinv[node];                                // prescale for next layer
    Xout[(size_t)node * D + lane] = f2bfbits(acc);
}

__global__ void __launch_bounds__(256)
agg_gemm_ln_kernel(const unsigned short* __restrict__ Xs,
                   const int* __restrict__ row_beg, const int* __restrict__ cnt,
                   const int* __restrict__ col, const float* __restrict__ dinv,
                   const float* __restrict__ W, const float* __restrict__ b,
                   const float* __restrict__ g, const float* __restrict__ be,
                   const int* __restrict__ flag, void* __restrict__ out, int n) {
    __shared__ float Wl[D * D];
    int t = threadIdx.x;
    for (int i = t; i < D * D; i += 256) Wl[i] = W[i];
    __syncthreads();
    int wid = t >> 6, lane = t & 63;
    int node = blockIdx.x * 4 + wid;
    if (node >= n) return;
    int   isf = *flag;
    float bl  = b[lane];
    float gl  = g[lane];
    float bel = be[lane];
    float x8[8];
    aggregate8(Xs, row_beg, cnt, col, dinv, node, lane, x8);
    float acc = wave_gemm(Wl, x8, lane) + bl;
    float s = acc;
#pragma unroll
    for (int off = 32; off > 0; off >>= 1) s += __shfl_xor(s, off, 64);
    float mu  = s * (1.f / 64.f);
    float dfe = acc - mu;
    float v   = dfe * dfe;
#pragma unroll
    for (int off = 32; off > 0; off >>= 1) v += __shfl_xor(v, off, 64);
    float var = v * (1.f / 64.f);
    float r   = rsqrtf(var + 1e-5f);
    float o   = dfe * r * gl + bel;
    size_t oi = (size_t)node * D + lane;
    if (isf) ((float*)out)[oi] = o;
    else     ((unsigned short*)out)[oi] = f2bfbits(o);
}

// ---- driver ----------------------------------------------------------------

extern "C" void kernel_launch(void* const* d_in, const int* in_sizes, int n_in,
                              void* d_out, int out_size, void* d_ws, size_t ws_size,
                              hipStream_t stream) {
    const void* X   = d_in[0];
    const void* W1  = d_in[1];
    const void* b1  = d_in[2];
    const void* W2  = d_in[3];
    const void* b2  = d_in[4];
    const void* W3  = d_in[5];
    const void* b3  = d_in[6];
    const void* pa  = d_in[7];
    const void* g   = d_in[8];
    const void* be  = d_in[9];
    const int*  ei  = (const int*)d_in[10];

    int N = in_sizes[0] / D;
    int E = in_sizes[10] / 2;
    int NB = (N + 63) >> BK_SHIFT;   // <= 1024 for N <= 65536
    int CH = (E + NBLK - 1) / NBLK;  // edges per radix block
    const int* src = ei;
    const int* dst = ei + E;

    char* p = (char*)d_ws;
    auto alloc = [&](size_t bytes) { void* q = (void*)p; p += (bytes + 255) & ~(size_t)255; return q; };
    int*            flag       = (int*)alloc(4);
    int*            H          = (int*)alloc((size_t)1024 * NBLK * 4);
    int*            T          = (int*)alloc(1024 * 4);
    int*            bucket_beg = (int*)alloc(1025 * 4);
    int*            row_beg    = (int*)alloc((size_t)N * 4);
    int*            cnt        = (int*)alloc((size_t)N * 4);
    float*          dinv       = (float*)alloc((size_t)N * 4);
    int*            col        = (int*)alloc((size_t)E * 4);
    unsigned int*   tmp        = (unsigned int*)alloc((size_t)E * 4);
    float*          P          = (float*)alloc((size_t)(OPA + 1) * 4);
    unsigned short* Xs         = (unsigned short*)alloc((size_t)N * D * 2);
    unsigned short* Xs2        = (unsigned short*)alloc((size_t)N * D * 2);
    (void)ws_size; (void)n_in; (void)out_size;

    sniff_kernel<<<1, 64, 0, stream>>>((const unsigned short*)W1, flag);
    cvt_params_kernel<<<1, 256, 0, stream>>>(W1, b1, W2, b2, W3, b3, pa, g, be, flag, P);

    binA1_kernel<<<NBLK, 256, 0, stream>>>(dst, E, NB, CH, H);
    binA2_kernel<<<NB, 256, 0, stream>>>(H, T);
    binA3_kernel<<<1, 1024, 0, stream>>>(T, bucket_beg, NB);
    binA4_kernel<<<NBLK, 256, 0, stream>>>(src, dst, H, bucket_beg, tmp, E, NB, CH);
    binB_kernel<<<NB, 256, 0, stream>>>(tmp, bucket_beg, row_beg, cnt, dinv, col, N);

    int nwb = (N * D + 255) / 256;   // one wave per node
    int ngb = (N + 3) / 4;           // 4 nodes per 256-thread block (HW-balanced)

    prescale_kernel<<<nwb, 256, 0, stream>>>(X, dinv, flag, Xs, N);

    agg_gemm_kernel   <<<ngb, 256, 0, stream>>>(Xs,  row_beg, cnt, col, dinv, P + OW1, P + OB1, P + OPA, Xs2, N);
    agg_gemm_kernel   <<<ngb, 256, 0, stream>>>(Xs2, row_beg, cnt, col, dinv, P + OW2, P + OB2, P + OPA, Xs,  N);
    agg_gemm_ln_kernel<<<ngb, 256, 0, stream>>>(Xs,  row_beg, cnt, col, dinv, P + OW3, P + OB3, P + OG, P + OBE, flag, d_out, N);
}

// Round 9
// 364.203 us; speedup vs baseline: 1.0730x; 1.0730x over previous
//
#include <hip/hip_runtime.h>

#define D 64
#define BK_SHIFT 6              // 64 nodes per bucket
#define BK_CAP 8192             // staged entries per bucket (mean ~1600)
#define NBLK 256                // radix pass blocks
#define PAD_SLACK 2048          // per-bucket col padding slack (64 nodes * <=31 + round)

__device__ __forceinline__ float bfbits2f(unsigned short b) {
    union { unsigned int u; float f; } c;
    c.u = ((unsigned int)b) << 16;
    return c.f;
}

__device__ __forceinline__ unsigned short f2bfbits(float f) {
    union { float f; unsigned int u; } c;
    c.f = f;
    unsigned int u = c.u;
    unsigned int lsb = (u >> 16) & 1u;
    u += 0x7fffu + lsb;           // round-to-nearest-even
    return (unsigned short)(u >> 16);
}

__device__ __forceinline__ float ldmix(const void* p, size_t i, int isf32) {
    return isf32 ? ((const float*)p)[i] : bfbits2f(((const unsigned short*)p)[i]);
}

// ---- dtype sniff -----------------------------------------------------------
__global__ void sniff_kernel(const unsigned short* __restrict__ W, int* __restrict__ flag) {
    int t = threadIdx.x;
    bool bad = false;
    for (int i = t; i < 256; i += 64) {
        float v = bfbits2f(W[i]);
        if (!(v == v) || fabsf(v) > 1e4f) bad = true;
    }
    unsigned long long m = __ballot(bad);
    if (t == 0) *flag = (m != 0ull) ? 1 : 0;
}

// ---- param conversion ------------------------------------------------------
#define OW1 0
#define OW2 4096
#define OW3 8192
#define OB1 12288
#define OB2 12352
#define OB3 12416
#define OG  12480
#define OBE 12544
#define OPA 12608

__global__ void cvt_params_kernel(const void* W1, const void* b1, const void* W2, const void* b2,
                                  const void* W3, const void* b3, const void* pa, const void* g,
                                  const void* be, const int* __restrict__ flag,
                                  float* __restrict__ P) {
    int isf = *flag;
    int t = threadIdx.x;                 // one block of 256
    for (int i = t; i < D * D; i += 256) {
        P[OW1 + i] = ldmix(W1, i, isf);
        P[OW2 + i] = ldmix(W2, i, isf);
        P[OW3 + i] = ldmix(W3, i, isf);
    }
    if (t < D) {
        P[OB1 + t] = ldmix(b1, t, isf);
        P[OB2 + t] = ldmix(b2, t, isf);
        P[OB3 + t] = ldmix(b3, t, isf);
        P[OG  + t] = ldmix(g,  t, isf);
        P[OBE + t] = ldmix(be, t, isf);
    }
    if (t == 0) P[OPA] = ldmix(pa, 0, isf);
}

// ---- deterministic two-pass radix binning (no global atomics) --------------
// H layout: H[bucket * NBLK + block]

__global__ void binA1_kernel(const int* __restrict__ dst, int E, int NB, int CH,
                             int* __restrict__ H) {
    __shared__ int h[1024];
    int t = threadIdx.x, bb = blockIdx.x;
    for (int i = t; i < NB; i += 256) h[i] = 0;
    __syncthreads();
    int beg = bb * CH, end = beg + CH; if (end > E) end = E;
    for (int e = beg + t; e < end; e += 256)
        atomicAdd(&h[dst[e] >> BK_SHIFT], 1);
    __syncthreads();
    for (int i = t; i < NB; i += 256) H[i * NBLK + bb] = h[i];
}

// per-bucket exclusive scan of the NBLK block-counts; T[b] = bucket total
__global__ void binA2_kernel(int* __restrict__ H, int* __restrict__ T) {
    __shared__ int ws[4];
    __shared__ int wx[4];
    int b = blockIdx.x, t = threadIdx.x;
    int lane = t & 63, wid = t >> 6;
    int v = H[b * NBLK + t];
    int incl = v;
#pragma unroll
    for (int off = 1; off < 64; off <<= 1) {
        int u = __shfl_up(incl, off, 64);
        if (lane >= off) incl += u;
    }
    if (lane == 63) ws[wid] = incl;
    __syncthreads();
    if (t == 0) {
        int s = 0;
#pragma unroll
        for (int j = 0; j < 4; ++j) { wx[j] = s; s += ws[j]; }
        T[b] = s;
    }
    __syncthreads();
    H[b * NBLK + t] = wx[wid] + incl - v;
}

// single-block scan of bucket totals -> bucket_beg
__global__ void binA3_kernel(const int* __restrict__ T, int* __restrict__ bucket_beg, int NB) {
    __shared__ int tile[1024];
    int t = threadIdx.x;
    int v = (t < NB) ? T[t] : 0;
    tile[t] = v;
    __syncthreads();
    for (int off = 1; off < 1024; off <<= 1) {
        int add = (t >= off) ? tile[t - off] : 0;
        __syncthreads();
        tile[t] += add;
        __syncthreads();
    }
    if (t < NB) bucket_beg[t] = tile[t] - v;
    if (t == NB - 1) bucket_beg[NB] = tile[t];
}

// scatter edges into bucket-grouped tmp via LDS cursors (deterministic ranges)
__global__ void binA4_kernel(const int* __restrict__ src, const int* __restrict__ dst,
                             const int* __restrict__ H, const int* __restrict__ bucket_beg,
                             unsigned int* __restrict__ tmp, int E, int NB, int CH) {
    __shared__ int O[1024];
    int t = threadIdx.x, bb = blockIdx.x;
    for (int i = t; i < NB; i += 256) O[i] = bucket_beg[i] + H[i * NBLK + bb];
    __syncthreads();
    int beg = bb * CH, end = beg + CH; if (end > E) end = E;
    for (int e = beg + t; e < end; e += 256) {
        int d = dst[e];
        int p = atomicAdd(&O[d >> BK_SHIFT], 1);
        tmp[p] = ((unsigned int)src[e] << BK_SHIFT) | (unsigned int)(d & 63);
    }
}

// one block per bucket: per-node count + padded scan + L2-local scatter +
// pad-fill with zero-row index N + fused layer-1 prescale
__global__ void binB_kernel(const unsigned int* __restrict__ tmp, const int* __restrict__ bucket_beg,
                            int* __restrict__ row_beg, int* __restrict__ cnt,
                            float* __restrict__ dinv, int* __restrict__ col,
                            const void* __restrict__ X, const int* __restrict__ flag,
                            unsigned short* __restrict__ Xs, int N) {
    __shared__ unsigned int ent[BK_CAP];
    __shared__ int lv[64], lpv[64], lpe[64], lcur[64];
    __shared__ float ldv[64];
    int b = blockIdx.x, t = threadIdx.x;
    int beg = bucket_beg[b], end = bucket_beg[b + 1];
    int colbase = beg + b * PAD_SLACK;
    int m = end - beg;
    bool staged = (m <= BK_CAP);
    if (t < 64) lv[t] = 0;
    __syncthreads();
    for (int i = t; i < m; i += 256) {
        unsigned int e = tmp[beg + i];
        if (staged) ent[i] = e;
        atomicAdd(&lv[e & 63u], 1);
    }
    __syncthreads();
    if (t < 64) {
        int v  = lv[t];
        int pv = (v + 31) & ~31;             // padded to multiple of 32
        int incl = pv;
#pragma unroll
        for (int off = 1; off < 64; off <<= 1) {
            int u = __shfl_up(incl, off, 64);
            if (t >= off) incl += u;
        }
        int pexcl = incl - pv;
        lpv[t]  = pv;
        lpe[t]  = pexcl;
        lcur[t] = pexcl;
        float dv = rsqrtf((float)(v + 1));
        ldv[t] = dv;
        int node = b * 64 + t;
        if (node < N) {
            row_beg[node] = colbase + pexcl;
            cnt[node]     = pv;              // padded count (loop bound)
            dinv[node]    = dv;
        }
    }
    __syncthreads();
    for (int i = t; i < m; i += 256) {
        unsigned int e = staged ? ent[i] : tmp[beg + i];
        int p = atomicAdd(&lcur[e & 63u], 1);
        col[colbase + p] = (int)(e >> BK_SHIFT);
    }
    // pad fill: positions [v, pv) of each node get the zero-row index N
    for (int i = t; i < 64 * 32; i += 256) {
        int nl = i >> 5, j = i & 31;
        int idx = lv[nl] + j;
        if (idx < lpv[nl]) col[colbase + lpe[nl] + idx] = N;
    }
    // fused layer-1 prescale: Xs[node][f] = bf16(dinv * X[node][f])
    int isf = *flag;
    for (int i = t; i < 64 * 64; i += 256) {
        int nl = i >> 6, f = i & 63;
        int node = b * 64 + nl;
        if (node < N)
            Xs[(size_t)node * D + f] = f2bfbits(ldv[nl] * ldmix(X, (size_t)node * D + f, isf));
    }
}

// ---- feature kernels -------------------------------------------------------

__device__ __forceinline__ void acc8(float* a, uint4 v) {
    a[0] += bfbits2f((unsigned short)(v.x & 0xffffu));
    a[1] += bfbits2f((unsigned short)(v.x >> 16));
    a[2] += bfbits2f((unsigned short)(v.y & 0xffffu));
    a[3] += bfbits2f((unsigned short)(v.y >> 16));
    a[4] += bfbits2f((unsigned short)(v.z & 0xffffu));
    a[5] += bfbits2f((unsigned short)(v.z >> 16));
    a[6] += bfbits2f((unsigned short)(v.w & 0xffffu));
    a[7] += bfbits2f((unsigned short)(v.w >> 16));
}

// static-trip gather: pcnt is a multiple of 32; pad entries point at the
// all-zero row N. 4 row-loads per chunk, edge indices via tiny broadcast
// col reads (8 lanes share an address) -- no shuffles, no masks.
__device__ __forceinline__ void aggregate32(const unsigned short* __restrict__ Xs,
                                            int beg, int pcnt,
                                            const int* __restrict__ col,
                                            float dn, int node, int lane,
                                            float* __restrict__ x8) {
    const int slot = lane >> 3;
    const int sub  = lane & 7;
    uint4 sv = *((const uint4*)(Xs + ((size_t)node << 6)) + sub);   // self loop (early)
    float a[8];
#pragma unroll
    for (int j = 0; j < 8; ++j) a[j] = 0.f;
    for (int c = 0; c < pcnt; c += 32) {
        const int* cb = col + beg + c;
        int s0 = cb[slot];
        int s1 = cb[8  + slot];
        int s2 = cb[16 + slot];
        int s3 = cb[24 + slot];
        uint4 v0 = *((const uint4*)(Xs + ((size_t)s0 << 6)) + sub);
        uint4 v1 = *((const uint4*)(Xs + ((size_t)s1 << 6)) + sub);
        uint4 v2 = *((const uint4*)(Xs + ((size_t)s2 << 6)) + sub);
        uint4 v3 = *((const uint4*)(Xs + ((size_t)s3 << 6)) + sub);
        acc8(a, v0);
        acc8(a, v1);
        acc8(a, v2);
        acc8(a, v3);
    }
    // reduce the 8 row-slots (flip lane bits 3..5; sub preserved)
#pragma unroll
    for (int off = 8; off < 64; off <<= 1) {
#pragma unroll
        for (int j = 0; j < 8; ++j) a[j] += __shfl_xor(a[j], off, 64);
    }
    acc8(a, sv);
#pragma unroll
    for (int j = 0; j < 8; ++j) x8[j] = dn * a[j];
}

// wave GEMM with 4-way accumulator ILP; feature k lives in lane k>>3, elem k&7
__device__ __forceinline__ float wave_gemm(const float* __restrict__ Wl, const float* x8, int lane) {
    float acc0 = 0.f, acc1 = 0.f, acc2 = 0.f, acc3 = 0.f;
#pragma unroll
    for (int k = 0; k < D; k += 4) {
        acc0 = fmaf(__shfl(x8[(k    ) & 7], (k    ) >> 3, 64), Wl[(k    ) * D + lane], acc0);
        acc1 = fmaf(__shfl(x8[(k + 1) & 7], (k + 1) >> 3, 64), Wl[(k + 1) * D + lane], acc1);
        acc2 = fmaf(__shfl(x8[(k + 2) & 7], (k + 2) >> 3, 64), Wl[(k + 2) * D + lane], acc2);
        acc3 = fmaf(__shfl(x8[(k + 3) & 7], (k + 3) >> 3, 64), Wl[(k + 3) * D + lane], acc3);
    }
    return (acc0 + acc1) + (acc2 + acc3);
}

__global__ void __launch_bounds__(256)
agg_gemm_kernel(const unsigned short* __restrict__ Xs,
                const int* __restrict__ row_beg, const int* __restrict__ cnt,
                const int* __restrict__ col, const float* __restrict__ dinv,
                const float* __restrict__ W, const float* __restrict__ b,
                const float* __restrict__ pa,
                unsigned short* __restrict__ Xout, int n) {
    __shared__ float Wl[D * D];
    int t = threadIdx.x;
    for (int i = t; i < D * D; i += 256) Wl[i] = W[i];
    __syncthreads();
    int wid = t >> 6, lane = t & 63;
    int node = blockIdx.x * 4 + wid;
    if (node >= n) return;
    float bl = b[lane];
    float a  = pa[0];
    float dn = dinv[node];
    float x8[8];
    aggregate32(Xs, row_beg[node], cnt[node], col, dn, node, lane, x8);
    float acc = wave_gemm(Wl, x8, lane) + bl;
    acc = (acc >= 0.f) ? acc : a * acc;
    acc *= dn;                                        // prescale for next layer
    Xout[(size_t)node * D + lane] = f2bfbits(acc);
}

__global__ void __launch_bounds__(256)
agg_gemm_ln_kernel(const unsigned short* __restrict__ Xs,
                   const int* __restrict__ row_beg, const int* __restrict__ cnt,
                   const int* __restrict__ col, const float* __restrict__ dinv,
                   const float* __restrict__ W, const float* __restrict__ b,
                   const float* __restrict__ g, const float* __restrict__ be,
                   const int* __restrict__ flag, void* __restrict__ out, int n) {
    __shared__ float Wl[D * D];
    int t = threadIdx.x;
    for (int i = t; i < D * D; i += 256) Wl[i] = W[i];
    __syncthreads();
    int wid = t >> 6, lane = t & 63;
    int node = blockIdx.x * 4 + wid;
    if (node >= n) return;
    int   isf = *flag;
    float bl  = b[lane];
    float gl  = g[lane];
    float bel = be[lane];
    float x8[8];
    aggregate32(Xs, row_beg[node], cnt[node], col, dinv[node], node, lane, x8);
    float acc = wave_gemm(Wl, x8, lane) + bl;
    float s = acc;
#pragma unroll
    for (int off = 32; off > 0; off >>= 1) s += __shfl_xor(s, off, 64);
    float mu  = s * (1.f / 64.f);
    float dfe = acc - mu;
    float v   = dfe * dfe;
#pragma unroll
    for (int off = 32; off > 0; off >>= 1) v += __shfl_xor(v, off, 64);
    float var = v * (1.f / 64.f);
    float r   = rsqrtf(var + 1e-5f);
    float o   = dfe * r * gl + bel;
    size_t oi = (size_t)node * D + lane;
    if (isf) ((float*)out)[oi] = o;
    else     ((unsigned short*)out)[oi] = f2bfbits(o);
}

// ---- driver ----------------------------------------------------------------

extern "C" void kernel_launch(void* const* d_in, const int* in_sizes, int n_in,
                              void* d_out, int out_size, void* d_ws, size_t ws_size,
                              hipStream_t stream) {
    const void* X   = d_in[0];
    const void* W1  = d_in[1];
    const void* b1  = d_in[2];
    const void* W2  = d_in[3];
    const void* b2  = d_in[4];
    const void* W3  = d_in[5];
    const void* b3  = d_in[6];
    const void* pa  = d_in[7];
    const void* g   = d_in[8];
    const void* be  = d_in[9];
    const int*  ei  = (const int*)d_in[10];

    int N = in_sizes[0] / D;
    int E = in_sizes[10] / 2;
    int NB = (N + 63) >> BK_SHIFT;   // <= 1024 for N <= 65536
    int CH = (E + NBLK - 1) / NBLK;  // edges per radix block
    const int* src = ei;
    const int* dst = ei + E;

    char* p = (char*)d_ws;
    auto alloc = [&](size_t bytes) { void* q = (void*)p; p += (bytes + 255) & ~(size_t)255; return q; };
    int*            flag       = (int*)alloc(4);
    int*            H          = (int*)alloc((size_t)1024 * NBLK * 4);
    int*            T          = (int*)alloc(1024 * 4);
    int*            bucket_beg = (int*)alloc(1025 * 4);
    int*            row_beg    = (int*)alloc((size_t)N * 4);
    int*            cnt        = (int*)alloc((size_t)N * 4);
    float*          dinv       = (float*)alloc((size_t)N * 4);
    int*            col        = (int*)alloc(((size_t)E + (size_t)NB * PAD_SLACK) * 4);
    unsigned int*   tmp        = (unsigned int*)alloc((size_t)E * 4);
    float*          P          = (float*)alloc((size_t)(OPA + 1) * 4);
    unsigned short* Xs         = (unsigned short*)alloc((size_t)(N + 1) * D * 2);
    unsigned short* Xs2        = (unsigned short*)alloc((size_t)(N + 1) * D * 2);
    (void)ws_size; (void)n_in; (void)out_size;

    // zero row (index N) for pad edges
    (void)hipMemsetAsync(Xs  + (size_t)N * D, 0, D * 2, stream);
    (void)hipMemsetAsync(Xs2 + (size_t)N * D, 0, D * 2, stream);

    sniff_kernel<<<1, 64, 0, stream>>>((const unsigned short*)W1, flag);
    cvt_params_kernel<<<1, 256, 0, stream>>>(W1, b1, W2, b2, W3, b3, pa, g, be, flag, P);

    binA1_kernel<<<NBLK, 256, 0, stream>>>(dst, E, NB, CH, H);
    binA2_kernel<<<NB, 256, 0, stream>>>(H, T);
    binA3_kernel<<<1, 1024, 0, stream>>>(T, bucket_beg, NB);
    binA4_kernel<<<NBLK, 256, 0, stream>>>(src, dst, H, bucket_beg, tmp, E, NB, CH);
    binB_kernel<<<NB, 256, 0, stream>>>(tmp, bucket_beg, row_beg, cnt, dinv, col, X, flag, Xs, N);

    int ngb = (N + 3) / 4;           // 4 nodes per 256-thread block (HW-balanced)

    agg_gemm_kernel   <<<ngb, 256, 0, stream>>>(Xs,  row_beg, cnt, col, dinv, P + OW1, P + OB1, P + OPA, Xs2, N);
    agg_gemm_kernel   <<<ngb, 256, 0, stream>>>(Xs2, row_beg, cnt, col, dinv, P + OW2, P + OB2, P + OPA, Xs,  N);
    agg_gemm_ln_kernel<<<ngb, 256, 0, stream>>>(Xs,  row_beg, cnt, col, dinv, P + OW3, P + OB3, P + OG, P + OBE, flag, d_out, N);
}

// Round 10
// 347.359 us; speedup vs baseline: 1.1251x; 1.0485x over previous
//
#include <hip/hip_runtime.h>

#define D 64
#define BK_SHIFT 6              // 64 nodes per bucket
#define BK_CAP 8192             // staged entries per bucket (mean ~1600)
#define NBLK 256                // radix pass blocks
#define PAD_SLACK 2048          // per-bucket col padding slack

__device__ __forceinline__ float bfbits2f(unsigned short b) {
    union { unsigned int u; float f; } c;
    c.u = ((unsigned int)b) << 16;
    return c.f;
}

__device__ __forceinline__ unsigned short f2bfbits(float f) {
    union { float f; unsigned int u; } c;
    c.f = f;
    unsigned int u = c.u;
    unsigned int lsb = (u >> 16) & 1u;
    u += 0x7fffu + lsb;           // round-to-nearest-even
    return (unsigned short)(u >> 16);
}

__device__ __forceinline__ float ldmix(const void* p, size_t i, int isf32) {
    return isf32 ? ((const float*)p)[i] : bfbits2f(((const unsigned short*)p)[i]);
}

// ---- dtype sniff -----------------------------------------------------------
__global__ void sniff_kernel(const unsigned short* __restrict__ W, int* __restrict__ flag) {
    int t = threadIdx.x;
    bool bad = false;
    for (int i = t; i < 256; i += 64) {
        float v = bfbits2f(W[i]);
        if (!(v == v) || fabsf(v) > 1e4f) bad = true;
    }
    unsigned long long m = __ballot(bad);
    if (t == 0) *flag = (m != 0ull) ? 1 : 0;
}

// ---- param conversion ------------------------------------------------------
#define OW1 0
#define OW2 4096
#define OW3 8192
#define OB1 12288
#define OB2 12352
#define OB3 12416
#define OG  12480
#define OBE 12544
#define OPA 12608

__global__ void cvt_params_kernel(const void* W1, const void* b1, const void* W2, const void* b2,
                                  const void* W3, const void* b3, const void* pa, const void* g,
                                  const void* be, const int* __restrict__ flag,
                                  float* __restrict__ P) {
    int isf = *flag;
    int t = threadIdx.x;                 // one block of 256
    for (int i = t; i < D * D; i += 256) {
        P[OW1 + i] = ldmix(W1, i, isf);
        P[OW2 + i] = ldmix(W2, i, isf);
        P[OW3 + i] = ldmix(W3, i, isf);
    }
    if (t < D) {
        P[OB1 + t] = ldmix(b1, t, isf);
        P[OB2 + t] = ldmix(b2, t, isf);
        P[OB3 + t] = ldmix(b3, t, isf);
        P[OG  + t] = ldmix(g,  t, isf);
        P[OBE + t] = ldmix(be, t, isf);
    }
    if (t == 0) P[OPA] = ldmix(pa, 0, isf);
}

// ---- deterministic two-pass radix binning (no global atomics) --------------
// H layout: H[bucket * NBLK + block]

__global__ void binA1_kernel(const int* __restrict__ dst, int E, int NB, int CH,
                             int* __restrict__ H) {
    __shared__ int h[1024];
    int t = threadIdx.x, bb = blockIdx.x;
    for (int i = t; i < NB; i += 256) h[i] = 0;
    __syncthreads();
    int beg = bb * CH, end = beg + CH; if (end > E) end = E;
    for (int e = beg + t; e < end; e += 256)
        atomicAdd(&h[dst[e] >> BK_SHIFT], 1);
    __syncthreads();
    for (int i = t; i < NB; i += 256) H[i * NBLK + bb] = h[i];
}

// per-bucket exclusive scan of the NBLK block-counts; T[b] = bucket total
__global__ void binA2_kernel(int* __restrict__ H, int* __restrict__ T) {
    __shared__ int ws[4];
    __shared__ int wx[4];
    int b = blockIdx.x, t = threadIdx.x;
    int lane = t & 63, wid = t >> 6;
    int v = H[b * NBLK + t];
    int incl = v;
#pragma unroll
    for (int off = 1; off < 64; off <<= 1) {
        int u = __shfl_up(incl, off, 64);
        if (lane >= off) incl += u;
    }
    if (lane == 63) ws[wid] = incl;
    __syncthreads();
    if (t == 0) {
        int s = 0;
#pragma unroll
        for (int j = 0; j < 4; ++j) { wx[j] = s; s += ws[j]; }
        T[b] = s;
    }
    __syncthreads();
    H[b * NBLK + t] = wx[wid] + incl - v;
}

// single-block scan of bucket totals -> bucket_beg
__global__ void binA3_kernel(const int* __restrict__ T, int* __restrict__ bucket_beg, int NB) {
    __shared__ int tile[1024];
    int t = threadIdx.x;
    int v = (t < NB) ? T[t] : 0;
    tile[t] = v;
    __syncthreads();
    for (int off = 1; off < 1024; off <<= 1) {
        int add = (t >= off) ? tile[t - off] : 0;
        __syncthreads();
        tile[t] += add;
        __syncthreads();
    }
    if (t < NB) bucket_beg[t] = tile[t] - v;
    if (t == NB - 1) bucket_beg[NB] = tile[t];
}

// scatter edges into bucket-grouped tmp via LDS cursors (deterministic ranges)
__global__ void binA4_kernel(const int* __restrict__ src, const int* __restrict__ dst,
                             const int* __restrict__ H, const int* __restrict__ bucket_beg,
                             unsigned int* __restrict__ tmp, int E, int NB, int CH) {
    __shared__ int O[1024];
    int t = threadIdx.x, bb = blockIdx.x;
    for (int i = t; i < NB; i += 256) O[i] = bucket_beg[i] + H[i * NBLK + bb];
    __syncthreads();
    int beg = bb * CH, end = beg + CH; if (end > E) end = E;
    for (int e = beg + t; e < end; e += 256) {
        int d = dst[e];
        int p = atomicAdd(&O[d >> BK_SHIFT], 1);
        tmp[p] = ((unsigned int)src[e] << BK_SHIFT) | (unsigned int)(d & 63);
    }
}

// one block per bucket: per-node count + padded scan + L2-local scatter +
// pad-fill with zero-row index N + fused layer-1 prescale
__global__ void binB_kernel(const unsigned int* __restrict__ tmp, const int* __restrict__ bucket_beg,
                            int* __restrict__ row_beg, int* __restrict__ cnt,
                            float* __restrict__ dinv, int* __restrict__ col,
                            const void* __restrict__ X, const int* __restrict__ flag,
                            unsigned short* __restrict__ Xs, int N) {
    __shared__ unsigned int ent[BK_CAP];
    __shared__ int lv[64], lpv[64], lpe[64], lcur[64];
    __shared__ float ldv[64];
    int b = blockIdx.x, t = threadIdx.x;
    int beg = bucket_beg[b], end = bucket_beg[b + 1];
    int colbase = beg + b * PAD_SLACK;
    int m = end - beg;
    bool staged = (m <= BK_CAP);
    if (t < 64) lv[t] = 0;
    __syncthreads();
    for (int i = t; i < m; i += 256) {
        unsigned int e = tmp[beg + i];
        if (staged) ent[i] = e;
        atomicAdd(&lv[e & 63u], 1);
    }
    __syncthreads();
    if (t < 64) {
        int v  = lv[t];
        int pv = (v + 31) & ~31;             // padded to multiple of 32
        int incl = pv;
#pragma unroll
        for (int off = 1; off < 64; off <<= 1) {
            int u = __shfl_up(incl, off, 64);
            if (t >= off) incl += u;
        }
        int pexcl = incl - pv;
        lpv[t]  = pv;
        lpe[t]  = pexcl;
        lcur[t] = pexcl;
        float dv = rsqrtf((float)(v + 1));
        ldv[t] = dv;
        int node = b * 64 + t;
        if (node < N) {
            row_beg[node] = colbase + pexcl;
            cnt[node]     = pv;              // padded count (loop bound)
            dinv[node]    = dv;
        }
    }
    __syncthreads();
    for (int i = t; i < m; i += 256) {
        unsigned int e = staged ? ent[i] : tmp[beg + i];
        int p = atomicAdd(&lcur[e & 63u], 1);
        col[colbase + p] = (int)(e >> BK_SHIFT);
    }
    // pad fill: positions [v, pv) of each node get the zero-row index N
    for (int i = t; i < 64 * 32; i += 256) {
        int nl = i >> 5, j = i & 31;
        int idx = lv[nl] + j;
        if (idx < lpv[nl]) col[colbase + lpe[nl] + idx] = N;
    }
    // fused layer-1 prescale: Xs[node][f] = bf16(dinv * X[node][f])
    int isf = *flag;
    for (int i = t; i < 64 * 64; i += 256) {
        int nl = i >> 6, f = i & 63;
        int node = b * 64 + nl;
        if (node < N)
            Xs[(size_t)node * D + f] = f2bfbits(ldv[nl] * ldmix(X, (size_t)node * D + f, isf));
    }
}

// ---- feature kernels -------------------------------------------------------

__device__ __forceinline__ void acc8(float* a, uint4 v) {
    a[0] += bfbits2f((unsigned short)(v.x & 0xffffu));
    a[1] += bfbits2f((unsigned short)(v.x >> 16));
    a[2] += bfbits2f((unsigned short)(v.y & 0xffffu));
    a[3] += bfbits2f((unsigned short)(v.y >> 16));
    a[4] += bfbits2f((unsigned short)(v.z & 0xffffu));
    a[5] += bfbits2f((unsigned short)(v.z >> 16));
    a[6] += bfbits2f((unsigned short)(v.w & 0xffffu));
    a[7] += bfbits2f((unsigned short)(v.w >> 16));
}

// paired static-trip gather: one wave aggregates TWO nodes, issuing both
// nodes' row loads back-to-back (~10 VMEM in flight) before consuming.
// pcnt multiples of 32; pad edges point at the all-zero row N.
__device__ __forceinline__ void agg_pair(const unsigned short* __restrict__ Xs,
                                         int begA, int pcA, int begB, int pcB,
                                         const int* __restrict__ col,
                                         float dnA, float dnB, int iA, int iB, int lane,
                                         float* __restrict__ xA, float* __restrict__ xB) {
    const int slot = lane >> 3;
    const int sub  = lane & 7;
    uint4 svA = *((const uint4*)(Xs + ((size_t)iA << 6)) + sub);   // self rows (early)
    uint4 svB = *((const uint4*)(Xs + ((size_t)iB << 6)) + sub);
    float a[8], b[8];
#pragma unroll
    for (int j = 0; j < 8; ++j) { a[j] = 0.f; b[j] = 0.f; }
    // first chunk of both nodes: issue all 8 row loads before consuming
    if (pcA > 0 && pcB > 0) {
        const int* cA = col + begA;
        const int* cB = col + begB;
        int sA0 = cA[slot], sA1 = cA[8 + slot], sA2 = cA[16 + slot], sA3 = cA[24 + slot];
        int sB0 = cB[slot], sB1 = cB[8 + slot], sB2 = cB[16 + slot], sB3 = cB[24 + slot];
        uint4 vA0 = *((const uint4*)(Xs + ((size_t)sA0 << 6)) + sub);
        uint4 vA1 = *((const uint4*)(Xs + ((size_t)sA1 << 6)) + sub);
        uint4 vA2 = *((const uint4*)(Xs + ((size_t)sA2 << 6)) + sub);
        uint4 vA3 = *((const uint4*)(Xs + ((size_t)sA3 << 6)) + sub);
        uint4 vB0 = *((const uint4*)(Xs + ((size_t)sB0 << 6)) + sub);
        uint4 vB1 = *((const uint4*)(Xs + ((size_t)sB1 << 6)) + sub);
        uint4 vB2 = *((const uint4*)(Xs + ((size_t)sB2 << 6)) + sub);
        uint4 vB3 = *((const uint4*)(Xs + ((size_t)sB3 << 6)) + sub);
        acc8(a, vA0); acc8(a, vA1); acc8(a, vA2); acc8(a, vA3);
        acc8(b, vB0); acc8(b, vB1); acc8(b, vB2); acc8(b, vB3);
    }
    // rare paths: deg 0 or deg > 32
    for (int c = (pcB > 0) ? 0 : -1; c == 0; c = 1) {   // pcA>0 && pcB==0 case
        if (pcA <= 0) break;
        if (pcB > 0) break;
        const int* cA = col + begA;
        int s0 = cA[slot], s1 = cA[8 + slot], s2 = cA[16 + slot], s3 = cA[24 + slot];
        uint4 v0 = *((const uint4*)(Xs + ((size_t)s0 << 6)) + sub);
        uint4 v1 = *((const uint4*)(Xs + ((size_t)s1 << 6)) + sub);
        uint4 v2 = *((const uint4*)(Xs + ((size_t)s2 << 6)) + sub);
        uint4 v3 = *((const uint4*)(Xs + ((size_t)s3 << 6)) + sub);
        acc8(a, v0); acc8(a, v1); acc8(a, v2); acc8(a, v3);
    }
    if (pcB > 0 && pcA <= 0) {
        const int* cB = col + begB;
        int s0 = cB[slot], s1 = cB[8 + slot], s2 = cB[16 + slot], s3 = cB[24 + slot];
        uint4 v0 = *((const uint4*)(Xs + ((size_t)s0 << 6)) + sub);
        uint4 v1 = *((const uint4*)(Xs + ((size_t)s1 << 6)) + sub);
        uint4 v2 = *((const uint4*)(Xs + ((size_t)s2 << 6)) + sub);
        uint4 v3 = *((const uint4*)(Xs + ((size_t)s3 << 6)) + sub);
        acc8(b, v0); acc8(b, v1); acc8(b, v2); acc8(b, v3);
    }
    for (int c = 32; c < pcA; c += 32) {
        const int* cA = col + begA + c;
        int s0 = cA[slot], s1 = cA[8 + slot], s2 = cA[16 + slot], s3 = cA[24 + slot];
        uint4 v0 = *((const uint4*)(Xs + ((size_t)s0 << 6)) + sub);
        uint4 v1 = *((const uint4*)(Xs + ((size_t)s1 << 6)) + sub);
        uint4 v2 = *((const uint4*)(Xs + ((size_t)s2 << 6)) + sub);
        uint4 v3 = *((const uint4*)(Xs + ((size_t)s3 << 6)) + sub);
        acc8(a, v0); acc8(a, v1); acc8(a, v2); acc8(a, v3);
    }
    for (int c = 32; c < pcB; c += 32) {
        const int* cB = col + begB + c;
        int s0 = cB[slot], s1 = cB[8 + slot], s2 = cB[16 + slot], s3 = cB[24 + slot];
        uint4 v0 = *((const uint4*)(Xs + ((size_t)s0 << 6)) + sub);
        uint4 v1 = *((const uint4*)(Xs + ((size_t)s1 << 6)) + sub);
        uint4 v2 = *((const uint4*)(Xs + ((size_t)s2 << 6)) + sub);
        uint4 v3 = *((const uint4*)(Xs + ((size_t)s3 << 6)) + sub);
        acc8(b, v0); acc8(b, v1); acc8(b, v2); acc8(b, v3);
    }
    // reduce the 8 row-slots for both nodes (flip lane bits 3..5)
#pragma unroll
    for (int off = 8; off < 64; off <<= 1) {
#pragma unroll
        for (int j = 0; j < 8; ++j) {
            a[j] += __shfl_xor(a[j], off, 64);
            b[j] += __shfl_xor(b[j], off, 64);
        }
    }
    acc8(a, svA);
    acc8(b, svB);
#pragma unroll
    for (int j = 0; j < 8; ++j) { xA[j] = dnA * a[j]; xB[j] = dnB * b[j]; }
}

// paired wave GEMM: each Wl value read once, used for both nodes (2x FMA ILP)
__device__ __forceinline__ void wave_gemm_pair(const float* __restrict__ Wl,
                                               const float* xA, const float* xB,
                                               int lane, float* oA, float* oB) {
    float a0 = 0.f, a1 = 0.f, b0 = 0.f, b1 = 0.f;
#pragma unroll
    for (int k = 0; k < D; k += 2) {
        float w0 = Wl[(k    ) * D + lane];
        float w1 = Wl[(k + 1) * D + lane];
        float xa0 = __shfl(xA[(k    ) & 7], (k    ) >> 3, 64);
        float xb0 = __shfl(xB[(k    ) & 7], (k    ) >> 3, 64);
        float xa1 = __shfl(xA[(k + 1) & 7], (k + 1) >> 3, 64);
        float xb1 = __shfl(xB[(k + 1) & 7], (k + 1) >> 3, 64);
        a0 = fmaf(xa0, w0, a0);
        b0 = fmaf(xb0, w0, b0);
        a1 = fmaf(xa1, w1, a1);
        b1 = fmaf(xb1, w1, b1);
    }
    *oA = a0 + a1;
    *oB = b0 + b1;
}

__global__ void __launch_bounds__(256)
agg_gemm_kernel(const unsigned short* __restrict__ Xs,
                const int* __restrict__ row_beg, const int* __restrict__ cnt,
                const int* __restrict__ col, const float* __restrict__ dinv,
                const float* __restrict__ W, const float* __restrict__ b,
                const float* __restrict__ pa,
                unsigned short* __restrict__ Xout, int n) {
    __shared__ float Wl[D * D];
    int t = threadIdx.x;
    for (int i = t; i < D * D; i += 256) Wl[i] = W[i];
    __syncthreads();
    int wid = t >> 6, lane = t & 63;
    int nodeA = blockIdx.x * 8 + wid * 2;
    int nodeB = nodeA + 1;
    if (nodeA >= n) return;
    bool vB = (nodeB < n);
    int  iA = nodeA, iB = vB ? nodeB : n;           // n = zero row (safe)
    int  begA = row_beg[nodeA], pcA = cnt[nodeA];
    int  begB = vB ? row_beg[nodeB] : 0, pcB = vB ? cnt[nodeB] : 0;
    float dnA = dinv[nodeA], dnB = vB ? dinv[nodeB] : 0.f;
    float bl = b[lane];
    float pr = pa[0];
    float xA[8], xB[8];
    agg_pair(Xs, begA, pcA, begB, pcB, col, dnA, dnB, iA, iB, lane, xA, xB);
    float accA, accB;
    wave_gemm_pair(Wl, xA, xB, lane, &accA, &accB);
    accA += bl; accB += bl;
    accA = (accA >= 0.f) ? accA : pr * accA;
    accB = (accB >= 0.f) ? accB : pr * accB;
    accA *= dnA; accB *= dnB;                        // prescale for next layer
    Xout[(size_t)nodeA * D + lane] = f2bfbits(accA);
    if (vB) Xout[(size_t)nodeB * D + lane] = f2bfbits(accB);
}

__global__ void __launch_bounds__(256)
agg_gemm_ln_kernel(const unsigned short* __restrict__ Xs,
                   const int* __restrict__ row_beg, const int* __restrict__ cnt,
                   const int* __restrict__ col, const float* __restrict__ dinv,
                   const float* __restrict__ W, const float* __restrict__ b,
                   const float* __restrict__ g, const float* __restrict__ be,
                   const int* __restrict__ flag, void* __restrict__ out, int n) {
    __shared__ float Wl[D * D];
    int t = threadIdx.x;
    for (int i = t; i < D * D; i += 256) Wl[i] = W[i];
    __syncthreads();
    int wid = t >> 6, lane = t & 63;
    int nodeA = blockIdx.x * 8 + wid * 2;
    int nodeB = nodeA + 1;
    if (nodeA >= n) return;
    bool vB = (nodeB < n);
    int  iA = nodeA, iB = vB ? nodeB : n;
    int  begA = row_beg[nodeA], pcA = cnt[nodeA];
    int  begB = vB ? row_beg[nodeB] : 0, pcB = vB ? cnt[nodeB] : 0;
    float dnA = dinv[nodeA], dnB = vB ? dinv[nodeB] : 0.f;
    int   isf = *flag;
    float bl  = b[lane];
    float gl  = g[lane];
    float bel = be[lane];
    float xA[8], xB[8];
    agg_pair(Xs, begA, pcA, begB, pcB, col, dnA, dnB, iA, iB, lane, xA, xB);
    float accA, accB;
    wave_gemm_pair(Wl, xA, xB, lane, &accA, &accB);
    accA += bl; accB += bl;
    // LayerNorm both nodes across the wave (independent shuffles)
    float sA = accA, sB = accB;
#pragma unroll
    for (int off = 32; off > 0; off >>= 1) { sA += __shfl_xor(sA, off, 64); sB += __shfl_xor(sB, off, 64); }
    float muA = sA * (1.f / 64.f), muB = sB * (1.f / 64.f);
    float dA = accA - muA, dB = accB - muB;
    float vA2 = dA * dA, vB2 = dB * dB;
#pragma unroll
    for (int off = 32; off > 0; off >>= 1) { vA2 += __shfl_xor(vA2, off, 64); vB2 += __shfl_xor(vB2, off, 64); }
    float rA = rsqrtf(vA2 * (1.f / 64.f) + 1e-5f);
    float rB = rsqrtf(vB2 * (1.f / 64.f) + 1e-5f);
    float oA = dA * rA * gl + bel;
    float oB = dB * rB * gl + bel;
    size_t oiA = (size_t)nodeA * D + lane;
    size_t oiB = (size_t)nodeB * D + lane;
    if (isf) {
        ((float*)out)[oiA] = oA;
        if (vB) ((float*)out)[oiB] = oB;
    } else {
        ((unsigned short*)out)[oiA] = f2bfbits(oA);
        if (vB) ((unsigned short*)out)[oiB] = f2bfbits(oB);
    }
}

// ---- driver ----------------------------------------------------------------

extern "C" void kernel_launch(void* const* d_in, const int* in_sizes, int n_in,
                              void* d_out, int out_size, void* d_ws, size_t ws_size,
                              hipStream_t stream) {
    const void* X   = d_in[0];
    const void* W1  = d_in[1];
    const void* b1  = d_in[2];
    const void* W2  = d_in[3];
    const void* b2  = d_in[4];
    const void* W3  = d_in[5];
    const void* b3  = d_in[6];
    const void* pa  = d_in[7];
    const void* g   = d_in[8];
    const void* be  = d_in[9];
    const int*  ei  = (const int*)d_in[10];

    int N = in_sizes[0] / D;
    int E = in_sizes[10] / 2;
    int NB = (N + 63) >> BK_SHIFT;   // <= 1024 for N <= 65536
    int CH = (E + NBLK - 1) / NBLK;  // edges per radix block
    const int* src = ei;
    const int* dst = ei + E;

    char* p = (char*)d_ws;
    auto alloc = [&](size_t bytes) { void* q = (void*)p; p += (bytes + 255) & ~(size_t)255; return q; };
    int*            flag       = (int*)alloc(4);
    int*            H          = (int*)alloc((size_t)1024 * NBLK * 4);
    int*            T          = (int*)alloc(1024 * 4);
    int*            bucket_beg = (int*)alloc(1025 * 4);
    int*            row_beg    = (int*)alloc((size_t)N * 4);
    int*            cnt        = (int*)alloc((size_t)N * 4);
    float*          dinv       = (float*)alloc((size_t)N * 4);
    int*            col        = (int*)alloc(((size_t)E + (size_t)NB * PAD_SLACK) * 4);
    unsigned int*   tmp        = (unsigned int*)alloc((size_t)E * 4);
    float*          P          = (float*)alloc((size_t)(OPA + 1) * 4);
    unsigned short* Xs         = (unsigned short*)alloc((size_t)(N + 1) * D * 2);
    unsigned short* Xs2        = (unsigned short*)alloc((size_t)(N + 1) * D * 2);
    (void)ws_size; (void)n_in; (void)out_size;

    // zero row (index N) for pad edges
    (void)hipMemsetAsync(Xs  + (size_t)N * D, 0, D * 2, stream);
    (void)hipMemsetAsync(Xs2 + (size_t)N * D, 0, D * 2, stream);

    sniff_kernel<<<1, 64, 0, stream>>>((const unsigned short*)W1, flag);
    cvt_params_kernel<<<1, 256, 0, stream>>>(W1, b1, W2, b2, W3, b3, pa, g, be, flag, P);

    binA1_kernel<<<NBLK, 256, 0, stream>>>(dst, E, NB, CH, H);
    binA2_kernel<<<NB, 256, 0, stream>>>(H, T);
    binA3_kernel<<<1, 1024, 0, stream>>>(T, bucket_beg, NB);
    binA4_kernel<<<NBLK, 256, 0, stream>>>(src, dst, H, bucket_beg, tmp, E, NB, CH);
    binB_kernel<<<NB, 256, 0, stream>>>(tmp, bucket_beg, row_beg, cnt, dinv, col, X, flag, Xs, N);

    int ngb = (N + 7) / 8;           // 8 nodes per 256-thread block (2 per wave)

    agg_gemm_kernel   <<<ngb, 256, 0, stream>>>(Xs,  row_beg, cnt, col, dinv, P + OW1, P + OB1, P + OPA, Xs2, N);
    agg_gemm_kernel   <<<ngb, 256, 0, stream>>>(Xs2, row_beg, cnt, col, dinv, P + OW2, P + OB2, P + OPA, Xs,  N);
    agg_gemm_ln_kernel<<<ngb, 256, 0, stream>>>(Xs,  row_beg, cnt, col, dinv, P + OW3, P + OB3, P + OG, P + OBE, flag, d_out, N);
}